// Round 8
// baseline (241.457 us; speedup 1.0000x reference)
//
#include <hip/hip_runtime.h>

#define NB 4
#define NN 1024
#define CC 64
#define BPB (NN / 4)   // gemm blocks per batch = 256

// Kernel 1: per 4-row block:
//   yc[b,n,o] = sum_c x[b,n,c]*W0[o,c]
//   yr[b,n,o] = sum_c x[b,n,c]*W1[o,c]
//   partials[blk,c] = sum over the block's 4 rows of x[.,c]
__global__ void k_gemm(const float* __restrict__ x, const float* __restrict__ W0,
                       const float* __restrict__ W1,
                       float* __restrict__ yc, float* __restrict__ yr,
                       float* __restrict__ partials) {
    __shared__ float sW0[64][65];   // +1 pad: stride-64 col reads would be 32-way bank conflict
    __shared__ float sW1[64][65];
    __shared__ float sX[4][64];
    const int t = threadIdx.x;
    const int b = blockIdx.x / BPB;
    const int n0 = (blockIdx.x % BPB) * 4;
    for (int idx = t; idx < 64 * 64; idx += 256) {
        sW0[idx >> 6][idx & 63] = W0[idx];
        sW1[idx >> 6][idx & 63] = W1[idx];
    }
    const int o = t & 63, r = t >> 6;
    sX[r][o] = x[((size_t)(b * NN + n0 + r)) * CC + o];
    __syncthreads();
    float a0 = 0.f, a1 = 0.f;
    #pragma unroll
    for (int c = 0; c < 64; ++c) {
        const float xv = sX[r][c];
        a0 += xv * sW0[o][c];
        a1 += xv * sW1[o][c];
    }
    const size_t oidx = ((size_t)(b * NN + n0 + r)) * CC + o;
    yc[oidx] = a0;
    yr[oidx] = a1;
    if (r == 0)   // threads 0..63: column partial sum of this block's 4 rows
        partials[(size_t)blockIdx.x * 64 + o] =
            sX[0][o] + sX[1][o] + sX[2][o] + sX[3][o];
}

// Kernel 2 (tiny): reduce partials per batch -> xsum, then ysb[b,o] = xsum.W2[o,:] + bias[o]
__global__ void k_ysb(const float* __restrict__ partials, const float* __restrict__ W2,
                      const float* __restrict__ bias, float* __restrict__ ysb) {
    const int b = blockIdx.x;
    const int t = threadIdx.x;
    const int c = t & 63, g = t >> 6;   // 4 groups x 64 channels
    __shared__ float sPart[4][64];
    __shared__ float sXsum[64];
    float acc = 0.f;
    const float* pb = partials + (size_t)b * BPB * 64;
    for (int blk = g; blk < BPB; blk += 4)
        acc += pb[blk * 64 + c];
    sPart[g][c] = acc;
    __syncthreads();
    if (t < 64)
        sXsum[t] = sPart[0][t] + sPart[1][t] + sPart[2][t] + sPart[3][t];
    __syncthreads();
    if (t < 64) {
        float v = bias[t];               // bias shape (64,1) -> bias[o]
        const float* w = W2 + t * CC;
        #pragma unroll 8
        for (int cc = 0; cc < CC; ++cc) v += sXsum[cc] * w[cc];
        ysb[b * CC + t] = v;
    }
}

// Kernel 3: out[b,i,j,:] = yc[b,j,:] + yr[b,i,:] + ysb[b,:]
// R4-exact structure (best measured) with ONE change: plain stores instead of
// nontemporal. NT bypasses L2 write-combining; the 6.5 TB/s fill kernel uses
// plain stores. Single-variable experiment.
__global__ void k_bcast(const float4* __restrict__ yc4, const float4* __restrict__ yr4,
                        const float4* __restrict__ ysb4, float4* __restrict__ out4) {
    const int t  = threadIdx.x;
    const int o4 = t & 15;
    const int j0 = t >> 4;
    const int b  = blockIdx.x >> 10;     // / NN
    const int i  = blockIdx.x & (NN - 1);
    float4 yr = yr4[(size_t)(b * NN + i) * 16 + o4];
    const float4 ys = ysb4[b * 16 + o4];
    yr.x += ys.x; yr.y += ys.y; yr.z += ys.z; yr.w += ys.w;
    const float4* ycb = yc4 + (size_t)b * NN * 16;
    float4* ob = out4 + (size_t)(b * NN + i) * (NN * 16);
    #pragma unroll 4
    for (int j = j0; j < NN; j += 16) {
        float4 v = ycb[j * 16 + o4];
        v.x += yr.x; v.y += yr.y; v.z += yr.z; v.w += yr.w;
        ob[j * 16 + o4] = v;
    }
}

extern "C" void kernel_launch(void* const* d_in, const int* in_sizes, int n_in,
                              void* d_out, int out_size, void* d_ws, size_t ws_size,
                              hipStream_t stream) {
    const float* x    = (const float*)d_in[0];
    // d_in[1] = adj (unused by forward)
    const float* W0   = (const float*)d_in[2];
    const float* W1   = (const float*)d_in[3];
    const float* W2   = (const float*)d_in[4];
    const float* bias = (const float*)d_in[5];
    float* out = (float*)d_out;

    float* ws       = (float*)d_ws;
    float* ysb      = ws;                                   // 256 floats
    float* yc       = ws + 256;                             // 262144 floats
    float* yr       = yc + NB * NN * CC;                    // 262144 floats
    float* partials = yr + NB * NN * CC;                    // 1024*64 = 65536 floats

    k_gemm<<<NB * BPB, 256, 0, stream>>>(x, W0, W1, yc, yr, partials);
    k_ysb<<<NB, 256, 0, stream>>>(partials, W2, bias, ysb);
    k_bcast<<<NB * NN, 256, 0, stream>>>((const float4*)yc, (const float4*)yr,
                                         (const float4*)ysb, (float4*)out);
}

// Round 9
// 238.009 us; speedup vs baseline: 1.0145x; 1.0145x over previous
//
#include <hip/hip_runtime.h>

#define NB 4
#define NN 1024
#define CC 64
#define BPB (NN / 4)        // gemm blocks per batch = 256
#define IT 4                // rows per bcast block
#define JCH 64              // j-columns per chunk -> 1024 float4/chunk, 4 per thread
#define CHUNKS (NN / JCH)   // 16

typedef float f4_native __attribute__((ext_vector_type(4)));

// Kernel 1: per 4-row block:
//   yc[b,n,o] = sum_c x[b,n,c]*W0[o,c]
//   yr[b,n,o] = sum_c x[b,n,c]*W1[o,c]
//   partials[blk,c] = sum over the block's 4 rows of x[.,c]
__global__ void k_gemm(const float* __restrict__ x, const float* __restrict__ W0,
                       const float* __restrict__ W1,
                       float* __restrict__ yc, float* __restrict__ yr,
                       float* __restrict__ partials) {
    __shared__ float sW0[64][65];   // +1 pad: stride-64 col reads would be 32-way bank conflict
    __shared__ float sW1[64][65];
    __shared__ float sX[4][64];
    const int t = threadIdx.x;
    const int b = blockIdx.x / BPB;
    const int n0 = (blockIdx.x % BPB) * 4;
    for (int idx = t; idx < 64 * 64; idx += 256) {
        sW0[idx >> 6][idx & 63] = W0[idx];
        sW1[idx >> 6][idx & 63] = W1[idx];
    }
    const int o = t & 63, r = t >> 6;
    sX[r][o] = x[((size_t)(b * NN + n0 + r)) * CC + o];
    __syncthreads();
    float a0 = 0.f, a1 = 0.f;
    #pragma unroll
    for (int c = 0; c < 64; ++c) {
        const float xv = sX[r][c];
        a0 += xv * sW0[o][c];
        a1 += xv * sW1[o][c];
    }
    const size_t oidx = ((size_t)(b * NN + n0 + r)) * CC + o;
    yc[oidx] = a0;
    yr[oidx] = a1;
    if (r == 0)   // threads 0..63: column partial sum of this block's 4 rows
        partials[(size_t)blockIdx.x * 64 + o] =
            sX[0][o] + sX[1][o] + sX[2][o] + sX[3][o];
}

// Kernel 2 (tiny): reduce partials per batch -> xsum, then ysb[b,o] = xsum.W2[o,:] + bias[o]
__global__ void k_ysb(const float* __restrict__ partials, const float* __restrict__ W2,
                      const float* __restrict__ bias, float* __restrict__ ysb) {
    const int b = blockIdx.x;
    const int t = threadIdx.x;
    const int c = t & 63, g = t >> 6;   // 4 groups x 64 channels
    __shared__ float sPart[4][64];
    __shared__ float sXsum[64];
    float acc = 0.f;
    const float* pb = partials + (size_t)b * BPB * 64;
    for (int blk = g; blk < BPB; blk += 4)
        acc += pb[blk * 64 + c];
    sPart[g][c] = acc;
    __syncthreads();
    if (t < 64)
        sXsum[t] = sPart[0][t] + sPart[1][t] + sPart[2][t] + sPart[3][t];
    __syncthreads();
    if (t < 64) {
        float v = bias[t];               // bias shape (64,1) -> bias[o]
        const float* w = W2 + t * CC;
        #pragma unroll 8
        for (int cc = 0; cc < CC; ++cc) v += sXsum[cc] * w[cc];
        ysb[b * CC + t] = v;
    }
}

// Kernel 3: out[b,i,j,:] = yc[b,j,:] + yr[b,i,:] + ysb[b,:]
// Chunked register pipeline, no LDS/barriers: per 64-j chunk each thread holds
// its 4 yc float4s in registers (ping-pong A/B so next chunk's loads issue
// before current chunk's stores) and stores IT=4 rows in 16 KB sequential
// bursts per row (coarse bursts: R5/R6's per-instr row interleave fragmented
// the DRAM write stream). yc L2-read traffic: 1.07 GB -> 268 MB vs R4.
__global__ void k_bcast(const float4* __restrict__ yc4, const float4* __restrict__ yr4,
                        const float4* __restrict__ ysb4, float4* __restrict__ out4) {
    const int t  = threadIdx.x;
    const int o4 = t & 15;
    const int b  = blockIdx.x / (NN / IT);
    const int i0 = (blockIdx.x % (NN / IT)) * IT;

    const float4 ys = ysb4[b * 16 + o4];
    float4 yrr[IT];
    #pragma unroll
    for (int r = 0; r < IT; ++r) {
        float4 v = yr4[(size_t)(b * NN + i0 + r) * 16 + o4];
        yrr[r].x = v.x + ys.x; yrr[r].y = v.y + ys.y;
        yrr[r].z = v.z + ys.z; yrr[r].w = v.w + ys.w;
    }

    const float4* ycb   = yc4 + (size_t)b * NN * 16;
    float4*       obase = out4 + ((size_t)(b * NN + i0)) * (NN * 16);

#define BCAST_BODY(CUR, NXT, c)                                           \
    do {                                                                  \
        if ((c) + 1 < CHUNKS) {                                           \
            const float4* src = ycb + ((c) + 1) * (JCH * 16);             \
            _Pragma("unroll")                                             \
            for (int s = 0; s < 4; ++s) NXT[s] = src[t + 256 * s];        \
        }                                                                 \
        _Pragma("unroll")                                                 \
        for (int r = 0; r < IT; ++r) {                                    \
            float4* obr = obase + (size_t)r * (NN * 16) + (c) * (JCH * 16); \
            _Pragma("unroll")                                             \
            for (int s = 0; s < 4; ++s) {                                 \
                float4 w;                                                 \
                w.x = CUR[s].x + yrr[r].x; w.y = CUR[s].y + yrr[r].y;     \
                w.z = CUR[s].z + yrr[r].z; w.w = CUR[s].w + yrr[r].w;     \
                __builtin_nontemporal_store(*(const f4_native*)&w,        \
                                            (f4_native*)&obr[t + 256 * s]); \
            }                                                             \
        }                                                                 \
    } while (0)

    float4 sa[4], sb[4];
    #pragma unroll
    for (int s = 0; s < 4; ++s) sa[s] = ycb[t + 256 * s];
    for (int c = 0; c < CHUNKS; c += 2) {
        BCAST_BODY(sa, sb, c);
        BCAST_BODY(sb, sa, c + 1);
    }
#undef BCAST_BODY
}

extern "C" void kernel_launch(void* const* d_in, const int* in_sizes, int n_in,
                              void* d_out, int out_size, void* d_ws, size_t ws_size,
                              hipStream_t stream) {
    const float* x    = (const float*)d_in[0];
    // d_in[1] = adj (unused by forward)
    const float* W0   = (const float*)d_in[2];
    const float* W1   = (const float*)d_in[3];
    const float* W2   = (const float*)d_in[4];
    const float* bias = (const float*)d_in[5];
    float* out = (float*)d_out;

    float* ws       = (float*)d_ws;
    float* ysb      = ws;                                   // 256 floats
    float* yc       = ws + 256;                             // 262144 floats
    float* yr       = yc + NB * NN * CC;                    // 262144 floats
    float* partials = yr + NB * NN * CC;                    // 1024*64 = 65536 floats

    k_gemm<<<NB * BPB, 256, 0, stream>>>(x, W0, W1, yc, yr, partials);
    k_ysb<<<NB, 256, 0, stream>>>(partials, W2, bias, ysb);
    k_bcast<<<NB * (NN / IT), 256, 0, stream>>>((const float4*)yc, (const float4*)yr,
                                                (const float4*)ysb, (float4*)out);
}

// Round 10
// 232.776 us; speedup vs baseline: 1.0373x; 1.0225x over previous
//
#include <hip/hip_runtime.h>

#define NB 4
#define NN 1024
#define CC 64
#define BPB (NN / 4)   // gemm blocks per batch = 256

typedef float f4_native __attribute__((ext_vector_type(4)));

// Kernel 1: per 4-row block:
//   yc[b,n,o] = sum_c x[b,n,c]*W0[o,c]
//   yr[b,n,o] = sum_c x[b,n,c]*W1[o,c]
//   partials[blk,c] = sum over the block's 4 rows of x[.,c]
__global__ void k_gemm(const float* __restrict__ x, const float* __restrict__ W0,
                       const float* __restrict__ W1,
                       float* __restrict__ yc, float* __restrict__ yr,
                       float* __restrict__ partials) {
    __shared__ float sW0[64][65];   // +1 pad: stride-64 col reads would be 32-way bank conflict
    __shared__ float sW1[64][65];
    __shared__ float sX[4][64];
    const int t = threadIdx.x;
    const int b = blockIdx.x / BPB;
    const int n0 = (blockIdx.x % BPB) * 4;
    for (int idx = t; idx < 64 * 64; idx += 256) {
        sW0[idx >> 6][idx & 63] = W0[idx];
        sW1[idx >> 6][idx & 63] = W1[idx];
    }
    const int o = t & 63, r = t >> 6;
    sX[r][o] = x[((size_t)(b * NN + n0 + r)) * CC + o];
    __syncthreads();
    float a0 = 0.f, a1 = 0.f;
    #pragma unroll
    for (int c = 0; c < 64; ++c) {
        const float xv = sX[r][c];
        a0 += xv * sW0[o][c];
        a1 += xv * sW1[o][c];
    }
    const size_t oidx = ((size_t)(b * NN + n0 + r)) * CC + o;
    yc[oidx] = a0;
    yr[oidx] = a1;
    if (r == 0)   // threads 0..63: column partial sum of this block's 4 rows
        partials[(size_t)blockIdx.x * 64 + o] =
            sX[0][o] + sX[1][o] + sX[2][o] + sX[3][o];
}

// Kernel 2 (tiny): reduce partials per batch -> xsum, then ysb[b,o] = xsum.W2[o,:] + bias[o]
__global__ void k_ysb(const float* __restrict__ partials, const float* __restrict__ W2,
                      const float* __restrict__ bias, float* __restrict__ ysb) {
    const int b = blockIdx.x;
    const int t = threadIdx.x;
    const int c = t & 63, g = t >> 6;   // 4 groups x 64 channels
    __shared__ float sPart[4][64];
    __shared__ float sXsum[64];
    float acc = 0.f;
    const float* pb = partials + (size_t)b * BPB * 64;
    for (int blk = g; blk < BPB; blk += 4)
        acc += pb[blk * 64 + c];
    sPart[g][c] = acc;
    __syncthreads();
    if (t < 64)
        sXsum[t] = sPart[0][t] + sPart[1][t] + sPart[2][t] + sPart[3][t];
    __syncthreads();
    if (t < 64) {
        float v = bias[t];               // bias shape (64,1) -> bias[o]
        const float* w = W2 + t * CC;
        #pragma unroll 8
        for (int cc = 0; cc < CC; ++cc) v += sXsum[cc] * w[cc];
        ysb[b * CC + t] = v;
    }
}

// Kernel 3: out[b,i,j,:] = yc[b,j,:] + yr[b,i,:] + ysb[b,:]
// R4 structure with ONE change: each block handles two ADJACENT rows (i, i+1),
// whose output regions are contiguous. Per j-iteration: 1 yc load + 2 NT stores
// (64 KB apart). Halves yc L2-read bytes and read instructions per output byte
// while preserving R4's coalescing, burst shape, and 8 resident blocks/CU.
__global__ void k_bcast(const float4* __restrict__ yc4, const float4* __restrict__ yr4,
                        const float4* __restrict__ ysb4, float4* __restrict__ out4) {
    const int t  = threadIdx.x;
    const int o4 = t & 15;
    const int j0 = t >> 4;
    const int b  = blockIdx.x >> 9;          // / (NN/2)
    const int i0 = (blockIdx.x & (NN / 2 - 1)) * 2;
    const float4 ys = ysb4[b * 16 + o4];
    float4 yr0 = yr4[(size_t)(b * NN + i0) * 16 + o4];
    float4 yr1 = yr4[(size_t)(b * NN + i0 + 1) * 16 + o4];
    yr0.x += ys.x; yr0.y += ys.y; yr0.z += ys.z; yr0.w += ys.w;
    yr1.x += ys.x; yr1.y += ys.y; yr1.z += ys.z; yr1.w += ys.w;
    const float4* ycb = yc4 + (size_t)b * NN * 16;
    float4* ob0 = out4 + (size_t)(b * NN + i0) * (NN * 16);
    float4* ob1 = ob0 + (size_t)NN * 16;     // adjacent row: contiguous region
    #pragma unroll 4
    for (int j = j0; j < NN; j += 16) {
        const float4 v = ycb[j * 16 + o4];
        float4 w0, w1;
        w0.x = v.x + yr0.x; w0.y = v.y + yr0.y; w0.z = v.z + yr0.z; w0.w = v.w + yr0.w;
        w1.x = v.x + yr1.x; w1.y = v.y + yr1.y; w1.z = v.z + yr1.z; w1.w = v.w + yr1.w;
        __builtin_nontemporal_store(*(const f4_native*)&w0, (f4_native*)&ob0[j * 16 + o4]);
        __builtin_nontemporal_store(*(const f4_native*)&w1, (f4_native*)&ob1[j * 16 + o4]);
    }
}

extern "C" void kernel_launch(void* const* d_in, const int* in_sizes, int n_in,
                              void* d_out, int out_size, void* d_ws, size_t ws_size,
                              hipStream_t stream) {
    const float* x    = (const float*)d_in[0];
    // d_in[1] = adj (unused by forward)
    const float* W0   = (const float*)d_in[2];
    const float* W1   = (const float*)d_in[3];
    const float* W2   = (const float*)d_in[4];
    const float* bias = (const float*)d_in[5];
    float* out = (float*)d_out;

    float* ws       = (float*)d_ws;
    float* ysb      = ws;                                   // 256 floats
    float* yc       = ws + 256;                             // 262144 floats
    float* yr       = yc + NB * NN * CC;                    // 262144 floats
    float* partials = yr + NB * NN * CC;                    // 1024*64 = 65536 floats

    k_gemm<<<NB * BPB, 256, 0, stream>>>(x, W0, W1, yc, yr, partials);
    k_ysb<<<NB, 256, 0, stream>>>(partials, W2, bias, ysb);
    k_bcast<<<NB * (NN / 2), 256, 0, stream>>>((const float4*)yc, (const float4*)yr,
                                               (const float4*)ysb, (float4*)out);
}

// Round 11
// 212.633 us; speedup vs baseline: 1.1356x; 1.0947x over previous
//
#include <hip/hip_runtime.h>

#define NB 4
#define NN 1024
#define CC 64
#define BPB (NN / 4)   // gemm blocks per batch = 256

typedef float f4_native __attribute__((ext_vector_type(4)));

// Kernel 1: per 4-row block:
//   yc[b,n,o] = sum_c x[b,n,c]*W0[o,c]
//   yr[b,n,o] = sum_c x[b,n,c]*W1[o,c]
//   partials[blk,c] = sum over the block's 4 rows of x[.,c]
__global__ void k_gemm(const float* __restrict__ x, const float* __restrict__ W0,
                       const float* __restrict__ W1,
                       float* __restrict__ yc, float* __restrict__ yr,
                       float* __restrict__ partials) {
    __shared__ float sW0[64][65];   // +1 pad: stride-64 col reads would be 32-way bank conflict
    __shared__ float sW1[64][65];
    __shared__ float sX[4][64];
    const int t = threadIdx.x;
    const int b = blockIdx.x / BPB;
    const int n0 = (blockIdx.x % BPB) * 4;
    for (int idx = t; idx < 64 * 64; idx += 256) {
        sW0[idx >> 6][idx & 63] = W0[idx];
        sW1[idx >> 6][idx & 63] = W1[idx];
    }
    const int o = t & 63, r = t >> 6;
    sX[r][o] = x[((size_t)(b * NN + n0 + r)) * CC + o];
    __syncthreads();
    float a0 = 0.f, a1 = 0.f;
    #pragma unroll
    for (int c = 0; c < 64; ++c) {
        const float xv = sX[r][c];
        a0 += xv * sW0[o][c];
        a1 += xv * sW1[o][c];
    }
    const size_t oidx = ((size_t)(b * NN + n0 + r)) * CC + o;
    yc[oidx] = a0;
    yr[oidx] = a1;
    if (r == 0)   // threads 0..63: column partial sum of this block's 4 rows
        partials[(size_t)blockIdx.x * 64 + o] =
            sX[0][o] + sX[1][o] + sX[2][o] + sX[3][o];
}

// Kernel 2 (tiny): reduce partials per batch -> xsum, then ysb[b,o] = xsum.W2[o,:] + bias[o]
__global__ void k_ysb(const float* __restrict__ partials, const float* __restrict__ W2,
                      const float* __restrict__ bias, float* __restrict__ ysb) {
    const int b = blockIdx.x;
    const int t = threadIdx.x;
    const int c = t & 63, g = t >> 6;   // 4 groups x 64 channels
    __shared__ float sPart[4][64];
    __shared__ float sXsum[64];
    float acc = 0.f;
    const float* pb = partials + (size_t)b * BPB * 64;
    for (int blk = g; blk < BPB; blk += 4)
        acc += pb[blk * 64 + c];
    sPart[g][c] = acc;
    __syncthreads();
    if (t < 64)
        sXsum[t] = sPart[0][t] + sPart[1][t] + sPart[2][t] + sPart[3][t];
    __syncthreads();
    if (t < 64) {
        float v = bias[t];               // bias shape (64,1) -> bias[o]
        const float* w = W2 + t * CC;
        #pragma unroll 8
        for (int cc = 0; cc < CC; ++cc) v += sXsum[cc] * w[cc];
        ysb[b * CC + t] = v;
    }
}

// Kernel 3: out[b,i,j,:] = yc[b,j,:] + yr[b,i,:] + ysb[b,:]
// R4-exact block/store geometry (1 row per block, 4096 blocks, sequential
// 64 KB NT store stream) with ONE change: loads are decoupled from stores by
// register ping-pong over 16 KB chunks — thread prefetches the NEXT chunk's
// 4 float4s while storing the CURRENT chunk, so no store waits on an
// in-flight load (R4's unroll-4 dep chain stalls on vmcnt per store).
__global__ void k_bcast(const float4* __restrict__ yc4, const float4* __restrict__ yr4,
                        const float4* __restrict__ ysb4, float4* __restrict__ out4) {
    const int t = threadIdx.x;
    const int o4 = t & 15;
    const int b = blockIdx.x >> 10;      // / NN
    const int i = blockIdx.x & (NN - 1);
    float4 yr = yr4[(size_t)(b * NN + i) * 16 + o4];
    const float4 ys = ysb4[b * 16 + o4];
    yr.x += ys.x; yr.y += ys.y; yr.z += ys.z; yr.w += ys.w;
    const float4* ycb = yc4 + (size_t)b * NN * 16;
    float4* ob = out4 + (size_t)(b * NN + i) * (NN * 16);

    // 16 chunks x 1024 float4 (16 KB); thread owns slots t, t+256, t+512, t+768.
    float4 sa[4], sb[4];
    #pragma unroll
    for (int s = 0; s < 4; ++s) sa[s] = ycb[t + 256 * s];

#define STORE_CHUNK(REGS, c)                                                 \
    do {                                                                     \
        float4* obc = ob + (c) * 1024;                                       \
        _Pragma("unroll")                                                    \
        for (int s = 0; s < 4; ++s) {                                        \
            float4 w;                                                        \
            w.x = REGS[s].x + yr.x; w.y = REGS[s].y + yr.y;                  \
            w.z = REGS[s].z + yr.z; w.w = REGS[s].w + yr.w;                  \
            __builtin_nontemporal_store(*(const f4_native*)&w,               \
                                        (f4_native*)&obc[t + 256 * s]);      \
        }                                                                    \
    } while (0)
#define PREFETCH(REGS, c)                                                    \
    do {                                                                     \
        const float4* src = ycb + (c) * 1024;                                \
        _Pragma("unroll")                                                    \
        for (int s = 0; s < 4; ++s) REGS[s] = src[t + 256 * s];              \
    } while (0)

    #pragma unroll
    for (int c = 0; c < 16; c += 2) {
        if (c + 1 < 16) PREFETCH(sb, c + 1);
        STORE_CHUNK(sa, c);
        if (c + 2 < 16) PREFETCH(sa, c + 2);
        STORE_CHUNK(sb, c + 1);
    }
#undef STORE_CHUNK
#undef PREFETCH
}

extern "C" void kernel_launch(void* const* d_in, const int* in_sizes, int n_in,
                              void* d_out, int out_size, void* d_ws, size_t ws_size,
                              hipStream_t stream) {
    const float* x    = (const float*)d_in[0];
    // d_in[1] = adj (unused by forward)
    const float* W0   = (const float*)d_in[2];
    const float* W1   = (const float*)d_in[3];
    const float* W2   = (const float*)d_in[4];
    const float* bias = (const float*)d_in[5];
    float* out = (float*)d_out;

    float* ws       = (float*)d_ws;
    float* ysb      = ws;                                   // 256 floats
    float* yc       = ws + 256;                             // 262144 floats
    float* yr       = yc + NB * NN * CC;                    // 262144 floats
    float* partials = yr + NB * NN * CC;                    // 1024*64 = 65536 floats

    k_gemm<<<NB * BPB, 256, 0, stream>>>(x, W0, W1, yc, yr, partials);
    k_ysb<<<NB, 256, 0, stream>>>(partials, W2, bias, ysb);
    k_bcast<<<NB * NN, 256, 0, stream>>>((const float4*)yc, (const float4*)yr,
                                         (const float4*)ysb, (float4*)out);
}